// Round 1
// baseline (764.694 us; speedup 1.0000x reference)
//
#include <hip/hip_runtime.h>
#include <math.h>

#define T_SEQ   2048
#define EDIM    512
#define NHEADS  8
#define DHEAD   64
#define BATCH   4
#define WIN     128
#define TOPK    96

// ---------------------------------------------------------------------------
// GEMM: C = A (MxK) * B^T (B is NxK, row-major) + bias[N]
// MODE 0: C row-major [M,N]
// MODE 1: C scattered to [B,H,T,D]: m=b*T+t, n=h*64+d -> ((b*H+h)*T+t)*64+d
// 64x64 tile, K-step 16, 256 threads, each thread computes 4x4.
// ---------------------------------------------------------------------------
template <int MODE>
__global__ __launch_bounds__(256) void gemm_bt(const float* __restrict__ A,
                                               const float* __restrict__ Bw,
                                               const float* __restrict__ bias,
                                               float* __restrict__ C,
                                               int M, int N, int K)
{
    __shared__ float As[16][68];   // [k][m], pad to 68: 16B-aligned rows, 2-way-max bank aliasing
    __shared__ float Bs[16][68];   // [k][n]

    const int m0  = blockIdx.x * 64;
    const int n0  = blockIdx.y * 64;
    const int tid = threadIdx.x;
    const int tm  = tid >> 4;      // 0..15
    const int tn  = tid & 15;      // 0..15

    float acc[4][4] = {};

    for (int k0 = 0; k0 < K; k0 += 16) {
#pragma unroll
        for (int s = 0; s < 4; s++) {
            const int i  = tid + 256 * s;      // 0..1023
            const int r  = i >> 4;             // 0..63
            const int kk = i & 15;             // 0..15
            As[kk][r] = A[(size_t)(m0 + r) * K + k0 + kk];
            Bs[kk][r] = Bw[(size_t)(n0 + r) * K + k0 + kk];
        }
        __syncthreads();

#pragma unroll
        for (int kt = 0; kt < 16; kt++) {
            const float4 a = *(const float4*)(&As[kt][tm * 4]);
            const float4 b = *(const float4*)(&Bs[kt][tn * 4]);
            const float av[4] = {a.x, a.y, a.z, a.w};
            const float bv[4] = {b.x, b.y, b.z, b.w};
#pragma unroll
            for (int i = 0; i < 4; i++)
#pragma unroll
                for (int j = 0; j < 4; j++)
                    acc[i][j] += av[i] * bv[j];
        }
        __syncthreads();
    }

    // epilogue
#pragma unroll
    for (int i = 0; i < 4; i++) {
        const int m = m0 + tm * 4 + i;
#pragma unroll
        for (int j = 0; j < 4; j++) {
            const int n = n0 + tn * 4 + j;
            const float val = acc[i][j] + bias[n];
            if (MODE == 0) {
                C[(size_t)m * N + n] = val;
            } else {
                const int b = m >> 11;            // T=2048
                const int t = m & (T_SEQ - 1);
                const int h = n >> 6;             // D=64
                const int d = n & 63;
                C[(((size_t)(b * NHEADS + h)) * T_SEQ + t) * DHEAD + d] = val;
            }
        }
    }
}

// ---------------------------------------------------------------------------
// Attention: one block (128 threads) per (b,h,query).
// Keys kk = q-127+j, j=0..127 (valid if kk>=0). Score (q_sq dropped — row
// constant, invariant for both top-k and softmax):
//   s_j = (q.k - 0.5*|k|^2) / sigma^2
// Top-96 via bitonic sort of 128 scores in LDS (ascending, kth = srt[32]).
// kth = -inf when <96 valid keys -> keep all valid (matches -inf>=-inf ref).
// ---------------------------------------------------------------------------
__global__ __launch_bounds__(128) void attn_kernel(const float* __restrict__ q,
                                                   const float* __restrict__ k,
                                                   const float* __restrict__ v,
                                                   const float* __restrict__ log_sigma,
                                                   float* __restrict__ att)
{
    const int idx = blockIdx.x;
    const int qi  = idx & (T_SEQ - 1);
    const int bh  = idx >> 11;         // (b*8+h)
    const int h   = bh & 7;
    const int tid = threadIdx.x;

    __shared__ float qs[DHEAD];
    __shared__ float srt[128];
    __shared__ float probs[128];
    __shared__ float part[DHEAD];

    const size_t head_base = (size_t)bh * T_SEQ * DHEAD;
    const float* qrow = q + head_base + (size_t)qi * DHEAD;

    if (tid < DHEAD) qs[tid] = qrow[tid];
    __syncthreads();

    // load q into registers (float4 x16)
    float4 qr[16];
#pragma unroll
    for (int i = 0; i < 16; i++) qr[i] = ((const float4*)qs)[i];

    const float inv_s2 = expf(-2.0f * log_sigma[h]);  // 1/sigma^2

    const int kk    = qi - (WIN - 1) + tid;
    const bool valid = (kk >= 0);

    float s = -INFINITY;
    if (valid) {
        const float4* krow = (const float4*)(k + head_base + (size_t)kk * DHEAD);
        float dot = 0.f, ksq = 0.f;
#pragma unroll
        for (int i = 0; i < 16; i++) {
            const float4 kv = krow[i];
            dot += qr[i].x * kv.x + qr[i].y * kv.y + qr[i].z * kv.z + qr[i].w * kv.w;
            ksq += kv.x * kv.x + kv.y * kv.y + kv.z * kv.z + kv.w * kv.w;
        }
        s = (dot - 0.5f * ksq) * inv_s2;
    }

    srt[tid] = s;

    // bitonic sort ascending, 128 elements, 128 threads
    for (int size = 2; size <= 128; size <<= 1) {
        for (int stride = size >> 1; stride > 0; stride >>= 1) {
            __syncthreads();
            const int p = tid ^ stride;
            if (p > tid) {
                const float x = srt[tid];
                const float y = srt[p];
                const bool up = ((tid & size) == 0);
                if (up ? (x > y) : (x < y)) { srt[tid] = y; srt[p] = x; }
            }
        }
    }
    __syncthreads();

    const float kth  = srt[128 - TOPK];   // 96th largest
    const float vmax = srt[127];          // row max (finite: kk=qi always valid)
    __syncthreads();

    const float p = (valid && s >= kth) ? expf(s - vmax) : 0.0f;
    probs[tid] = p;
    srt[tid]   = p;
    __syncthreads();
#pragma unroll
    for (int off = 64; off > 0; off >>= 1) {
        if (tid < off) srt[tid] += srt[tid + off];
        __syncthreads();
    }
    const float invsum = 1.0f / srt[0];

    // PV: wave w handles j in [w*64, w*64+64), lane d = tid&63
    const int w = tid >> 6;
    const int d = tid & 63;
    float acc = 0.f;
    const int jbase = w * 64;
#pragma unroll 4
    for (int jj = 0; jj < 64; jj++) {
        const int j  = jbase + jj;
        const float pj = probs[j];          // wave-uniform broadcast
        if (pj != 0.0f) {                   // wave-uniform branch: skip dropped keys
            const int kj = qi - (WIN - 1) + j;
            acc += pj * v[head_base + (size_t)kj * DHEAD + d];
        }
    }
    if (w == 1) part[d] = acc;
    __syncthreads();
    if (w == 0) {
        const float o = (acc + part[d]) * invsum;
        const int b = bh >> 3;
        att[((size_t)(b * T_SEQ + qi)) * EDIM + h * DHEAD + d] = o;
    }
}

// ---------------------------------------------------------------------------
extern "C" void kernel_launch(void* const* d_in, const int* in_sizes, int n_in,
                              void* d_out, int out_size, void* d_ws, size_t ws_size,
                              hipStream_t stream)
{
    const float* x      = (const float*)d_in[0];
    const float* Wq     = (const float*)d_in[1];
    const float* bq     = (const float*)d_in[2];
    const float* Wk     = (const float*)d_in[3];
    const float* bk     = (const float*)d_in[4];
    const float* Wv     = (const float*)d_in[5];
    const float* bv     = (const float*)d_in[6];
    const float* Wo     = (const float*)d_in[7];
    const float* bo     = (const float*)d_in[8];
    const float* logsig = (const float*)d_in[9];

    const int M = BATCH * T_SEQ;   // 8192
    const size_t mat = (size_t)M * EDIM;

    float* qb = (float*)d_ws;
    float* kb = qb + mat;
    float* vb = kb + mat;
    float* ab = vb + mat;

    dim3 gg(M / 64, EDIM / 64), gb(256);
    gemm_bt<1><<<gg, gb, 0, stream>>>(x, Wq, bq, qb, M, EDIM, EDIM);
    gemm_bt<1><<<gg, gb, 0, stream>>>(x, Wk, bk, kb, M, EDIM, EDIM);
    gemm_bt<1><<<gg, gb, 0, stream>>>(x, Wv, bv, vb, M, EDIM, EDIM);

    attn_kernel<<<BATCH * NHEADS * T_SEQ, 128, 0, stream>>>(qb, kb, vb, logsig, ab);

    gemm_bt<0><<<gg, gb, 0, stream>>>(ab, Wo, bo, (float*)d_out, M, EDIM, EDIM);
}

// Round 2
// 324.276 us; speedup vs baseline: 2.3582x; 2.3582x over previous
//
#include <hip/hip_runtime.h>
#include <math.h>

#define T_SEQ   2048
#define EDIM    512
#define NHEADS  8
#define DHEAD   64
#define BATCH   4
#define WIN     128
#define TOPK    96
#define M_ROWS  (BATCH*T_SEQ)   // 8192

typedef _Float16 f16;
typedef f16 f16x2 __attribute__((ext_vector_type(2)));
typedef f16 f16x4 __attribute__((ext_vector_type(4)));
typedef f16 f16x8 __attribute__((ext_vector_type(8)));
typedef float f32x4 __attribute__((ext_vector_type(4)));

#define GLD_LDS(gp, lp) \
    __builtin_amdgcn_global_load_lds((const __attribute__((address_space(1))) void*)(gp), \
                                     (__attribute__((address_space(3))) void*)(lp), 16, 0, 0)

// ---------------------------------------------------------------------------
// fp32 -> f16 conversion of x, Wq, Wk, Wv, Wo (fixed sizes), 4 elems/thread.
// segments: x[4194304] -> xh ; Wq/Wk/Wv[262144 each] -> wqkvh ; Wo -> woh
// ---------------------------------------------------------------------------
__global__ __launch_bounds__(256) void convert_all(
    const float* __restrict__ x,  const float* __restrict__ wq,
    const float* __restrict__ wk, const float* __restrict__ wv,
    const float* __restrict__ wo,
    f16* __restrict__ xh, f16* __restrict__ wqkvh, f16* __restrict__ woh)
{
    long i = ((long)blockIdx.x * 256 + threadIdx.x) * 4;
    const float* src; f16* dst; long off;
    if      (i < 4194304L) { src = x;  dst = xh;            off = i;            }
    else if (i < 4456448L) { src = wq; dst = wqkvh;         off = i - 4194304L; }
    else if (i < 4718592L) { src = wk; dst = wqkvh + 262144; off = i - 4456448L; }
    else if (i < 4980736L) { src = wv; dst = wqkvh + 524288; off = i - 4718592L; }
    else                   { src = wo; dst = woh;           off = i - 4980736L; }
    float4 v = *(const float4*)(src + off);
    f16x4 h; h.x = (f16)v.x; h.y = (f16)v.y; h.z = (f16)v.z; h.w = (f16)v.w;
    *(f16x4*)(dst + off) = h;
}

// ---------------------------------------------------------------------------
// f16 MFMA GEMM: C[m][n] = sum_k A[m][k]*W[n][k] + bias[n]
// A [Mx512] f16 row-major, W [Nx512] f16 row-major. 128x128 tile, BK=64,
// 256 threads (4 waves, 2x2 of 64x64). LDS staged in MFMA-fragment order via
// global_load_lds width=16: chunk (kp,ms) of 16 rows x 32 k, lane l holds
// row (l&15), k-offset (l>>4)*8 -> ds_read_b128 at lane*16 is the A-frag.
// MODE 0: C row-major fp32 [Mx512], bias b0.
// MODE 1: QKV scatter: matrix=n>>9 (dst C + matrix*4194304 as [B,H,T,D]),
//         bias selected from b0/b1/b2.
// ---------------------------------------------------------------------------
template <int MODE>
__global__ __launch_bounds__(256) void gemm_mfma(
    const f16* __restrict__ A, const f16* __restrict__ W,
    const float* __restrict__ b0, const float* __restrict__ b1,
    const float* __restrict__ b2, float* __restrict__ C)
{
    __shared__ f16 Ash[16 * 512];   // 16 chunks x 1KB
    __shared__ f16 Bsh[16 * 512];

    const int tid  = threadIdx.x;
    const int w    = tid >> 6;
    const int lane = tid & 63;
    const int m0   = blockIdx.x * 128;
    const int n0   = blockIdx.y * 128;
    const int K    = 512;
    const int lr   = lane & 15;
    const int lk8  = (lane >> 4) * 8;

    f32x4 acc[4][4];
#pragma unroll
    for (int i = 0; i < 4; i++)
#pragma unroll
        for (int j = 0; j < 4; j++) acc[i][j] = (f32x4){0.f, 0.f, 0.f, 0.f};

    const int wmi = (w & 1) * 4;   // m-subtile base index (x16 rows)
    const int wni = (w >> 1) * 4;  // n-subtile base index

    for (int k0 = 0; k0 < K; k0 += 64) {
#pragma unroll
        for (int cc = 0; cc < 4; cc++) {
            const int c  = w * 4 + cc;       // 0..15
            const int ms = c & 7, kp = c >> 3;
            const int kcol = k0 + kp * 32 + lk8;
            const f16* ga = A + (size_t)(m0 + ms * 16 + lr) * K + kcol;
            GLD_LDS(ga, Ash + c * 512);
            const f16* gb = W + (size_t)(n0 + ms * 16 + lr) * K + kcol;
            GLD_LDS(gb, Bsh + c * 512);
        }
        __syncthreads();

#pragma unroll
        for (int kp = 0; kp < 2; kp++) {
            f16x8 af[4], bf[4];
#pragma unroll
            for (int i = 0; i < 4; i++)
                af[i] = *(const f16x8*)(Ash + (kp * 8 + wmi + i) * 512 + lane * 8);
#pragma unroll
            for (int j = 0; j < 4; j++)
                bf[j] = *(const f16x8*)(Bsh + (kp * 8 + wni + j) * 512 + lane * 8);
#pragma unroll
            for (int i = 0; i < 4; i++)
#pragma unroll
                for (int j = 0; j < 4; j++)
                    acc[i][j] = __builtin_amdgcn_mfma_f32_16x16x32_f16(af[i], bf[j], acc[i][j], 0, 0, 0);
        }
        __syncthreads();
    }

    // epilogue: D row = quad*4+reg, col = lane&15
    const int quad = lane >> 4;
    if (MODE == 0) {
#pragma unroll
        for (int i = 0; i < 4; i++) {
#pragma unroll
            for (int j = 0; j < 4; j++) {
                const int n  = n0 + (w >> 1) * 64 + j * 16 + lr;
                const float bv = b0[n];
#pragma unroll
                for (int r = 0; r < 4; r++) {
                    const int m = m0 + (w & 1) * 64 + i * 16 + quad * 4 + r;
                    C[(size_t)m * 512 + n] = acc[i][j][r] + bv;
                }
            }
        }
    } else {
        const int mat = n0 >> 9;   // block-uniform
        const float* bias = (mat == 0) ? b0 : ((mat == 1) ? b1 : b2);
        float* dst = C + (size_t)mat * 4194304;
#pragma unroll
        for (int i = 0; i < 4; i++) {
#pragma unroll
            for (int j = 0; j < 4; j++) {
                const int n    = n0 + (w >> 1) * 64 + j * 16 + lr;
                const int ncol = n & 511;
                const int h    = ncol >> 6, d = n & 63;
                const float bv = bias[ncol];
#pragma unroll
                for (int r = 0; r < 4; r++) {
                    const int m = m0 + (w & 1) * 64 + i * 16 + quad * 4 + r;
                    const int b = m >> 11, t = m & (T_SEQ - 1);
                    dst[(((size_t)(b * NHEADS + h)) * T_SEQ + t) * DHEAD + d] = acc[i][j][r] + bv;
                }
            }
        }
    }
}

// ---------------------------------------------------------------------------
// Attention: block = 256 threads (4 waves) handles 64 queries of one (b,h).
// K/V window rows [q0-128, q0+63] (192) staged once as f16 in LDS (51 KB ->
// 3 blocks/CU). Wave w processes queries dq = w*16..w*16+15 with NO barriers:
//   lane = key (j=lane, j+64), f16x2 LDS dot with readlane-broadcast q,
//   shuffle-only bitonic sort of 128 scores (2 regs/lane, e = r*64+lane),
//   kth = rank 32, vmax = rank 127, probs + wave-reduce sum,
//   PV: lane = d, readlane-broadcast probs. q_sq dropped (row-constant).
// ---------------------------------------------------------------------------
__global__ __launch_bounds__(256) void attn_kernel(
    const float* __restrict__ qf, const float* __restrict__ kf,
    const float* __restrict__ vf, const float* __restrict__ log_sigma,
    f16* __restrict__ abh)
{
    __shared__ f16 Ks[192][66];
    __shared__ f16 Vs[192][66];
    __shared__ float ksqs[192];

    const int tid  = threadIdx.x;
    const int w    = tid >> 6;
    const int lane = tid & 63;
    const int q0   = blockIdx.x * 64;
    const int bh   = blockIdx.y;
    const int h    = bh & 7, b = bh >> 3;
    const size_t hb = (size_t)bh * (T_SEQ * DHEAD);
    const int ks0  = q0 - 128;

    // stage K,V (f32 global -> f16 LDS), zero rows with kidx<0
    for (int i = tid; i < 192 * 32; i += 256) {
        const int r  = i >> 5;
        const int dp = (i & 31) * 2;
        const int kidx = ks0 + r;
        float2 kv2 = {0.f, 0.f}, vv2 = {0.f, 0.f};
        if (kidx >= 0) {
            kv2 = *(const float2*)(kf + hb + (size_t)kidx * DHEAD + dp);
            vv2 = *(const float2*)(vf + hb + (size_t)kidx * DHEAD + dp);
        }
        f16x2 kh; kh.x = (f16)kv2.x; kh.y = (f16)kv2.y;
        f16x2 vh; vh.x = (f16)vv2.x; vh.y = (f16)vv2.y;
        *(f16x2*)&Ks[r][dp] = kh;
        *(f16x2*)&Vs[r][dp] = vh;
    }
    __syncthreads();
    if (tid < 192) {
        float s = 0.f;
#pragma unroll 16
        for (int d = 0; d < 64; d++) { const float kv = (float)Ks[tid][d]; s += kv * kv; }
        ksqs[tid] = s;
    }
    __syncthreads();

    const float inv_s2 = __expf(-2.0f * log_sigma[h]);

    for (int qi = 0; qi < 16; qi++) {
        const int dq = w * 16 + qi;       // 0..63
        const int q  = q0 + dq;

        // q row as packed f16 pairs: lane l holds (q[2*(l&31)], q[2*(l&31)+1])
        const float2 q2 = *(const float2*)(qf + hb + (size_t)q * DHEAD + 2 * (lane & 31));
        f16x2 qh; qh.x = (f16)q2.x; qh.y = (f16)q2.y;
        const int qbits = __builtin_bit_cast(int, qh);

        const int c0 = dq + 1 + lane;     // staged row for key j=lane
        const int c1 = c0 + 64;           // key j=lane+64
        float dot0 = 0.f, dot1 = 0.f;
#pragma unroll
        for (int dp = 0; dp < 32; dp++) {
            const int qb = __builtin_amdgcn_readlane(qbits, dp);
            const f16x2 qq = __builtin_bit_cast(f16x2, qb);
            const f16x2 k0 = *(const f16x2*)&Ks[c0][2 * dp];
            const f16x2 k1 = *(const f16x2*)&Ks[c1][2 * dp];
            dot0 += (float)k0.x * (float)qq.x + (float)k0.y * (float)qq.y;
            dot1 += (float)k1.x * (float)qq.x + (float)k1.y * (float)qq.y;
        }
        const int kidx0 = q - 127 + lane;
        const int kidx1 = kidx0 + 64;
        const float s0raw = (kidx0 >= 0) ? (dot0 - 0.5f * ksqs[c0]) * inv_s2 : -INFINITY;
        const float s1raw = (kidx1 >= 0) ? (dot1 - 0.5f * ksqs[c1]) * inv_s2 : -INFINITY;

        // shuffle-only bitonic sort ascending of 128 values, e = r*64+lane
        float a0 = s0raw, a1 = s1raw;
#pragma unroll
        for (int size = 2; size <= 64; size <<= 1) {
#pragma unroll
            for (int d = size >> 1; d >= 1; d >>= 1) {
                const bool lower = ((lane & d) == 0);
                const bool up0 = ((lane & size) == 0);
                const bool up1 = (size == 64) ? false : up0;
                const float t0 = __shfl_xor(a0, d);
                const float t1 = __shfl_xor(a1, d);
                a0 = (up0 == lower) ? fminf(a0, t0) : fmaxf(a0, t0);
                a1 = (up1 == lower) ? fminf(a1, t1) : fmaxf(a1, t1);
            }
        }
        { const float lo = fminf(a0, a1), hi = fmaxf(a0, a1); a0 = lo; a1 = hi; }
#pragma unroll
        for (int d = 32; d >= 1; d >>= 1) {
            const bool lower = ((lane & d) == 0);
            const float t0 = __shfl_xor(a0, d);
            const float t1 = __shfl_xor(a1, d);
            a0 = lower ? fminf(a0, t0) : fmaxf(a0, t0);
            a1 = lower ? fminf(a1, t1) : fmaxf(a1, t1);
        }

        const float kth  = __uint_as_float(__builtin_amdgcn_readlane(__float_as_uint(a0), 32));
        const float vmax = __uint_as_float(__builtin_amdgcn_readlane(__float_as_uint(a1), 63));

        const float p0 = (s0raw >= kth) ? __expf(s0raw - vmax) : 0.f;
        const float p1 = (s1raw >= kth) ? __expf(s1raw - vmax) : 0.f;

        float ps = p0 + p1;
#pragma unroll
        for (int d = 32; d >= 1; d >>= 1) ps += __shfl_xor(ps, d);
        const float inv_sum = 1.0f / ps;

        // PV: lane = output dim d
        float acc = 0.f;
#pragma unroll 8
        for (int j = 0; j < 64; j++) {
            const float pj = __uint_as_float(__builtin_amdgcn_readlane(__float_as_uint(p0), j));
            acc += pj * (float)Vs[dq + 1 + j][lane];
        }
#pragma unroll 8
        for (int j = 0; j < 64; j++) {
            const float pj = __uint_as_float(__builtin_amdgcn_readlane(__float_as_uint(p1), j));
            acc += pj * (float)Vs[dq + 65 + j][lane];
        }
        abh[((size_t)(b * T_SEQ + q)) * EDIM + h * DHEAD + lane] = (f16)(acc * inv_sum);
    }
}

// ---------------------------------------------------------------------------
extern "C" void kernel_launch(void* const* d_in, const int* in_sizes, int n_in,
                              void* d_out, int out_size, void* d_ws, size_t ws_size,
                              hipStream_t stream)
{
    const float* x      = (const float*)d_in[0];
    const float* Wq     = (const float*)d_in[1];
    const float* bq     = (const float*)d_in[2];
    const float* Wk     = (const float*)d_in[3];
    const float* bk     = (const float*)d_in[4];
    const float* Wv     = (const float*)d_in[5];
    const float* bv     = (const float*)d_in[6];
    const float* Wo     = (const float*)d_in[7];
    const float* bo     = (const float*)d_in[8];
    const float* logsig = (const float*)d_in[9];

    // ws layout (all 16B aligned):
    f16*   xh    = (f16*)d_ws;             // 4,194,304 f16 (reused as abh later)
    f16*   wqkvh = xh + 4194304;           // 786,432 f16
    f16*   woh   = wqkvh + 786432;         // 262,144 f16
    float* qf    = (float*)(woh + 262144); // 4,194,304 f32
    float* kf    = qf + 4194304;
    float* vf    = kf + 4194304;
    f16*   abh   = xh;                     // alias: x dead after QKV GEMM

    convert_all<<<5120, 256, 0, stream>>>(x, Wq, Wk, Wv, Wo, xh, wqkvh, woh);

    // fused QKV: A=xh [8192x512], W=wqkvh [1536x512] -> qf/kf/vf [B,H,T,D]
    gemm_mfma<1><<<dim3(64, 12), 256, 0, stream>>>(xh, wqkvh, bq, bk, bv, qf);

    attn_kernel<<<dim3(T_SEQ / 64, BATCH * NHEADS), 256, 0, stream>>>(qf, kf, vf, logsig, abh);

    // output projection: A=abh, W=woh -> d_out [8192x512] fp32
    gemm_mfma<0><<<dim3(64, 4), 256, 0, stream>>>(abh, woh, bo, bo, bo, (float*)d_out);
}

// Round 3
// 191.993 us; speedup vs baseline: 3.9829x; 1.6890x over previous
//
#include <hip/hip_runtime.h>
#include <math.h>

#define T_SEQ   2048
#define EDIM    512
#define NHEADS  8
#define DHEAD   64
#define BATCH   4
#define WIN     128
#define TOPK    96

typedef _Float16 f16;
typedef f16 f16x2 __attribute__((ext_vector_type(2)));
typedef f16 f16x4 __attribute__((ext_vector_type(4)));
typedef f16 f16x8 __attribute__((ext_vector_type(8)));
typedef float f32x4 __attribute__((ext_vector_type(4)));

#define GLD_LDS(gp, lp) \
    __builtin_amdgcn_global_load_lds((const __attribute__((address_space(1))) void*)(gp), \
                                     (__attribute__((address_space(3))) void*)(lp), 16, 0, 0)

// ---------------------------------------------------------------------------
// fp32 -> f16 conversion of x, Wq, Wk, Wv, Wo. 4 elems/thread.
// ---------------------------------------------------------------------------
__global__ __launch_bounds__(256) void convert_all(
    const float* __restrict__ x,  const float* __restrict__ wq,
    const float* __restrict__ wk, const float* __restrict__ wv,
    const float* __restrict__ wo,
    f16* __restrict__ xh, f16* __restrict__ wqkvh, f16* __restrict__ woh)
{
    long i = ((long)blockIdx.x * 256 + threadIdx.x) * 4;
    const float* src; f16* dst; long off;
    if      (i < 4194304L) { src = x;  dst = xh;             off = i;            }
    else if (i < 4456448L) { src = wq; dst = wqkvh;          off = i - 4194304L; }
    else if (i < 4718592L) { src = wk; dst = wqkvh + 262144; off = i - 4456448L; }
    else if (i < 4980736L) { src = wv; dst = wqkvh + 524288; off = i - 4718592L; }
    else                   { src = wo; dst = woh;            off = i - 4980736L; }
    float4 v = *(const float4*)(src + off);
    f16x4 h; h.x = (f16)v.x; h.y = (f16)v.y; h.z = (f16)v.z; h.w = (f16)v.w;
    *(f16x4*)(dst + off) = h;
}

// ---------------------------------------------------------------------------
// |k|^2 per row of kh [B,H,T,64] f16 -> ksqg f32 [B*H*T]. 4 threads/row.
// ---------------------------------------------------------------------------
__global__ __launch_bounds__(256) void ksq_kernel(const f16* __restrict__ kh,
                                                  float* __restrict__ ksqg)
{
    const int i   = blockIdx.x * 256 + threadIdx.x;   // 262144
    const int row = i >> 2, part = i & 3;
    const f16* p = kh + (size_t)row * 64 + part * 16;
    const f16x8 a = ((const f16x8*)p)[0];
    const f16x8 b = ((const f16x8*)p)[1];
    float s = 0.f;
#pragma unroll
    for (int j = 0; j < 8; j++) {
        const float fa = (float)a[j], fb = (float)b[j];
        s += fa * fa + fb * fb;
    }
    s += __shfl_xor(s, 1);
    s += __shfl_xor(s, 2);
    if (part == 0) ksqg[row] = s;
}

// ---------------------------------------------------------------------------
// f16 MFMA GEMM (m97-pattern): C[m][n] = sum_k A[m][k]*W[n][k] + bias[n]
// 128x128 tile, BK=64, 256 threads. LDS staged in MFMA-fragment order via
// global_load_lds width=16.
// MODE 0: C0 row-major fp32 [Mx512], bias b0.
// MODE 1: QKV: matrix = n0>>9. Q,K -> f16 [B,H,T,64]; V -> f16 [B,H,64,T]
//         (pre-transposed for attention's PV B-operand).
// ---------------------------------------------------------------------------
template <int MODE>
__global__ __launch_bounds__(256) void gemm_mfma(
    const f16* __restrict__ A, const f16* __restrict__ W,
    const float* __restrict__ b0, const float* __restrict__ b1,
    const float* __restrict__ b2, float* __restrict__ C0,
    f16* __restrict__ cq, f16* __restrict__ ck, f16* __restrict__ cv)
{
    __shared__ f16 Ash[16 * 512];
    __shared__ f16 Bsh[16 * 512];

    const int tid  = threadIdx.x;
    const int w    = tid >> 6;
    const int lane = tid & 63;
    const int m0   = blockIdx.x * 128;
    const int n0   = blockIdx.y * 128;
    const int K    = 512;
    const int lr   = lane & 15;
    const int lk8  = (lane >> 4) * 8;

    f32x4 acc[4][4];
#pragma unroll
    for (int i = 0; i < 4; i++)
#pragma unroll
        for (int j = 0; j < 4; j++) acc[i][j] = (f32x4){0.f, 0.f, 0.f, 0.f};

    const int wmi = (w & 1) * 4;
    const int wni = (w >> 1) * 4;

    for (int k0 = 0; k0 < K; k0 += 64) {
#pragma unroll
        for (int cc = 0; cc < 4; cc++) {
            const int c  = w * 4 + cc;
            const int ms = c & 7, kp = c >> 3;
            const int kcol = k0 + kp * 32 + lk8;
            GLD_LDS(A + (size_t)(m0 + ms * 16 + lr) * K + kcol, Ash + c * 512);
            GLD_LDS(W + (size_t)(n0 + ms * 16 + lr) * K + kcol, Bsh + c * 512);
        }
        __syncthreads();

#pragma unroll
        for (int kp = 0; kp < 2; kp++) {
            f16x8 af[4], bf[4];
#pragma unroll
            for (int i = 0; i < 4; i++)
                af[i] = *(const f16x8*)(Ash + (kp * 8 + wmi + i) * 512 + lane * 8);
#pragma unroll
            for (int j = 0; j < 4; j++)
                bf[j] = *(const f16x8*)(Bsh + (kp * 8 + wni + j) * 512 + lane * 8);
#pragma unroll
            for (int i = 0; i < 4; i++)
#pragma unroll
                for (int j = 0; j < 4; j++)
                    acc[i][j] = __builtin_amdgcn_mfma_f32_16x16x32_f16(af[i], bf[j], acc[i][j], 0, 0, 0);
        }
        __syncthreads();
    }

    const int quad = lane >> 4;
    if (MODE == 0) {
#pragma unroll
        for (int i = 0; i < 4; i++) {
#pragma unroll
            for (int j = 0; j < 4; j++) {
                const int n  = n0 + (w >> 1) * 64 + j * 16 + lr;
                const float bv = b0[n];
#pragma unroll
                for (int r = 0; r < 4; r++) {
                    const int m = m0 + (w & 1) * 64 + i * 16 + quad * 4 + r;
                    C0[(size_t)m * 512 + n] = acc[i][j][r] + bv;
                }
            }
        }
    } else {
        const int mat = n0 >> 9;
        const float* bias = (mat == 0) ? b0 : ((mat == 1) ? b1 : b2);
#pragma unroll
        for (int i = 0; i < 4; i++) {
#pragma unroll
            for (int j = 0; j < 4; j++) {
                const int n    = n0 + (w >> 1) * 64 + j * 16 + lr;
                const int ncol = n & 511;
                const int h    = ncol >> 6, d = ncol & 63;
                const float bv = bias[ncol];
                if (mat < 2) {
                    f16* dst = (mat == 0) ? cq : ck;
#pragma unroll
                    for (int r = 0; r < 4; r++) {
                        const int m = m0 + (w & 1) * 64 + i * 16 + quad * 4 + r;
                        const int b = m >> 11, t = m & (T_SEQ - 1);
                        dst[((size_t)((b * NHEADS + h) * T_SEQ) + t) * 64 + d] =
                            (f16)(acc[i][j][r] + bv);
                    }
                } else {
                    const int mb = m0 + (w & 1) * 64 + i * 16 + quad * 4;
                    const int b = mb >> 11, t = mb & (T_SEQ - 1);
                    f16x4 pk;
#pragma unroll
                    for (int r = 0; r < 4; r++) pk[r] = (f16)(acc[i][j][r] + bv);
                    *(f16x4*)(cv + ((size_t)((b * NHEADS + h) * 64 + d)) * T_SEQ + t) = pk;
                }
            }
        }
    }
}

// ---------------------------------------------------------------------------
// Attention v3: block = 256 threads = 4 waves, handles (b,h) x 64 queries.
// Phases (LDS aliased, 75.5 KB -> 2 blocks/CU):
//  1. stage Qs[64][80], Ks[192][80] f16, ksqs[192] f32
//  2. QK^T MFMA (wave = 48-key n-strip) -> Sc[64][132] f32 (windowed, masked,
//     score = (q.k - 0.5|k|^2)/sigma^2; q_sq dropped: row-constant shift)
//  3. per-query (2 interleaved): exact top-96 kth via 32-step ballot binary
//     search on ordered uint bits; vmax = diagonal score (provably row max:
//     score monotone-decreasing in |q-k|^2); write P[64][200] f16 (aliases Qs/Ks)
//  4. stage Vt[64][200] f16 from pre-transposed V (aliases Sc)
//  5. PV MFMA (wave = 16-query m-tile) + ones-MFMA row sums; scale, write f16.
// ---------------------------------------------------------------------------
__global__ __launch_bounds__(256) void attn_v3(
    const f16* __restrict__ qh, const f16* __restrict__ kh,
    const f16* __restrict__ vtg, const float* __restrict__ ksqg,
    const float* __restrict__ logsig, f16* __restrict__ abh)
{
    __shared__ __align__(16) char smem[75520];
    f16*   Qs   = (f16*)smem;                 // [64][80]
    f16*   Ks   = (f16*)(smem + 10240);       // [192][80]
    f16*   P    = (f16*)smem;                 // [64][200] alias Qs+Ks
    float* Sc   = (float*)(smem + 40960);     // [64][132]
    f16*   Vt   = (f16*)(smem + 40960);       // [64][200] alias Sc
    float* ksqs = (float*)(smem + 74752);     // [192]

    const int tid = threadIdx.x, w = tid >> 6, lane = tid & 63;
    const int lr = lane & 15, quad = lane >> 4;
    const int q0 = blockIdx.x * 64, bh = blockIdx.y;
    const int h = bh & 7, b = bh >> 3;
    const size_t tb = (size_t)bh * T_SEQ;
    const int ks0 = q0 - 128;

    // ---- phase 1: stage Q, K, ksq ----
#pragma unroll
    for (int s = 0; s < 2; s++) {            // Qs: 512 chunks of 8 f16
        const int i = tid + 256 * s;
        const int row = i >> 3, ch = i & 7;
        f16x8 v = *(const f16x8*)(qh + (tb + q0 + row) * 64 + ch * 8);
        *(f16x8*)(Qs + row * 80 + ch * 8) = v;
    }
#pragma unroll
    for (int s = 0; s < 6; s++) {            // Ks: 1536 chunks
        const int i = tid + 256 * s;
        const int row = i >> 3, ch = i & 7;
        const int kg = ks0 + row;
        f16x8 v = {};
        if (kg >= 0) v = *(const f16x8*)(kh + (tb + kg) * 64 + ch * 8);
        *(f16x8*)(Ks + row * 80 + ch * 8) = v;
    }
    if (tid < 192) {
        const int kg = ks0 + tid;
        ksqs[tid] = (kg >= 0) ? ksqg[tb + kg] : 0.f;
    }
    __syncthreads();

    // ---- phase 2: QK^T, wave = n-strip of 48 keys ----
    f32x4 accQ[4][3];
#pragma unroll
    for (int i = 0; i < 4; i++)
#pragma unroll
        for (int jt = 0; jt < 3; jt++) accQ[i][jt] = (f32x4){0.f, 0.f, 0.f, 0.f};

    const int nb = w * 48;
#pragma unroll
    for (int kp = 0; kp < 2; kp++) {
        f16x8 bf[3];
#pragma unroll
        for (int jt = 0; jt < 3; jt++)
            bf[jt] = *(const f16x8*)(Ks + (nb + jt * 16 + lr) * 80 + kp * 32 + quad * 8);
#pragma unroll
        for (int i = 0; i < 4; i++) {
            const f16x8 af = *(const f16x8*)(Qs + (i * 16 + lr) * 80 + kp * 32 + quad * 8);
#pragma unroll
            for (int jt = 0; jt < 3; jt++)
                accQ[i][jt] = __builtin_amdgcn_mfma_f32_16x16x32_f16(af, bf[jt], accQ[i][jt], 0, 0, 0);
        }
    }
    const float inv_s2 = __expf(-2.0f * logsig[h]);
#pragma unroll
    for (int i = 0; i < 4; i++) {
#pragma unroll
        for (int jt = 0; jt < 3; jt++) {
            const int c  = nb + jt * 16 + lr;
            const float kq = ksqs[c];
            const int kg = ks0 + c;
#pragma unroll
            for (int r = 0; r < 4; r++) {
                const int dq = i * 16 + quad * 4 + r;
                const unsigned wc = (unsigned)(c - dq - 1);
                if (wc < 128u) {
                    const float sv = (kg >= 0) ? (accQ[i][jt][r] - 0.5f * kq) * inv_s2
                                               : -INFINITY;
                    Sc[dq * 132 + wc] = sv;
                }
            }
        }
    }
    __syncthreads();

    // ---- phase 3: top-96 threshold + probs, 2 queries interleaved ----
    const int wq = w * 16;
#pragma unroll 1
    for (int qp = 0; qp < 8; qp++) {
        const int dqA = wq + qp * 2, dqB = dqA + 1;
        const float s0A = Sc[dqA * 132 + lane], s1A = Sc[dqA * 132 + 64 + lane];
        const float s0B = Sc[dqB * 132 + lane], s1B = Sc[dqB * 132 + 64 + lane];
        // ordered keys: monotone uint transform of float
        const unsigned b0A = __float_as_uint(s0A), b1A = __float_as_uint(s1A);
        const unsigned b0B = __float_as_uint(s0B), b1B = __float_as_uint(s1B);
        const unsigned u0A = b0A ^ (unsigned)(((int)b0A >> 31) | 0x80000000);
        const unsigned u1A = b1A ^ (unsigned)(((int)b1A >> 31) | 0x80000000);
        const unsigned u0B = b0B ^ (unsigned)(((int)b0B >> 31) | 0x80000000);
        const unsigned u1B = b1B ^ (unsigned)(((int)b1B >> 31) | 0x80000000);
        // row max = diagonal score (lane 63 of s1)
        const float mA = __uint_as_float(__builtin_amdgcn_readlane(__float_as_uint(s1A), 63));
        const float mB = __uint_as_float(__builtin_amdgcn_readlane(__float_as_uint(s1B), 63));

        unsigned tA = 0u, tB = 0u;
#pragma unroll
        for (int bit = 31; bit >= 0; bit--) {
            const unsigned cA = tA | (1u << bit);
            const unsigned cB = tB | (1u << bit);
            const int nA = __popcll(__ballot(u0A >= cA)) + __popcll(__ballot(u1A >= cA));
            const int nB = __popcll(__ballot(u0B >= cB)) + __popcll(__ballot(u1B >= cB));
            if (nA >= TOPK) tA = cA;
            if (nB >= TOPK) tB = cB;
        }

        const float p0A = (u0A >= tA) ? __expf(s0A - mA) : 0.f;
        const float p1A = (u1A >= tA) ? __expf(s1A - mA) : 0.f;
        const float p0B = (u0B >= tB) ? __expf(s0B - mB) : 0.f;
        const float p1B = (u1B >= tB) ? __expf(s1B - mB) : 0.f;

        // window cols dq+1..dq+128 get probs; the other 64 cols get zeros
        P[dqA * 200 + dqA + 1 + lane]  = (f16)p0A;
        P[dqA * 200 + dqA + 65 + lane] = (f16)p1A;
        P[dqA * 200 + ((lane <= dqA) ? lane : lane + 128)] = (f16)0.f;
        P[dqB * 200 + dqB + 1 + lane]  = (f16)p0B;
        P[dqB * 200 + dqB + 65 + lane] = (f16)p1B;
        P[dqB * 200 + ((lane <= dqB) ? lane : lane + 128)] = (f16)0.f;
    }
    __syncthreads();

    // ---- phase 4: stage V^T (aliases Sc) ----
#pragma unroll
    for (int s = 0; s < 6; s++) {
        const int i = tid + 256 * s;          // 0..1535
        const int d = i / 24, ch = i % 24;
        const int t0 = ks0 + ch * 8;
        f16x8 vv = {};
        if (t0 >= 0) vv = *(const f16x8*)(vtg + ((size_t)bh * 64 + d) * T_SEQ + t0);
        *(f16x8*)(Vt + d * 200 + ch * 8) = vv;
    }
    __syncthreads();

    // ---- phase 5: PV MFMA, wave = m-tile w; ones-MFMA gives row sums ----
    f32x4 accO[4];
#pragma unroll
    for (int nt = 0; nt < 4; nt++) accO[nt] = (f32x4){0.f, 0.f, 0.f, 0.f};
    f32x4 accS = (f32x4){0.f, 0.f, 0.f, 0.f};
    f16x8 onesf;
#pragma unroll
    for (int j = 0; j < 8; j++) onesf[j] = (f16)1.0f;

#pragma unroll
    for (int ks = 0; ks < 6; ks++) {
        const f16x8 pf = *(const f16x8*)(P + (wq + lr) * 200 + ks * 32 + quad * 8);
#pragma unroll
        for (int nt = 0; nt < 4; nt++) {
            const f16x8 vf = *(const f16x8*)(Vt + (nt * 16 + lr) * 200 + ks * 32 + quad * 8);
            accO[nt] = __builtin_amdgcn_mfma_f32_16x16x32_f16(pf, vf, accO[nt], 0, 0, 0);
        }
        accS = __builtin_amdgcn_mfma_f32_16x16x32_f16(pf, onesf, accS, 0, 0, 0);
    }
    // every column of P*ones = row sum -> each lane already holds its rows' sums
    float inv[4];
#pragma unroll
    for (int r = 0; r < 4; r++) inv[r] = 1.0f / accS[r];

#pragma unroll
    for (int nt = 0; nt < 4; nt++) {
        const int d = nt * 16 + lr;
#pragma unroll
        for (int r = 0; r < 4; r++) {
            const int q = q0 + wq + quad * 4 + r;
            abh[((size_t)(b * T_SEQ + q)) * 512 + h * 64 + d] = (f16)(accO[nt][r] * inv[r]);
        }
    }
}

// ---------------------------------------------------------------------------
extern "C" void kernel_launch(void* const* d_in, const int* in_sizes, int n_in,
                              void* d_out, int out_size, void* d_ws, size_t ws_size,
                              hipStream_t stream)
{
    const float* x      = (const float*)d_in[0];
    const float* Wq     = (const float*)d_in[1];
    const float* bq     = (const float*)d_in[2];
    const float* Wk     = (const float*)d_in[3];
    const float* bk     = (const float*)d_in[4];
    const float* Wv     = (const float*)d_in[5];
    const float* bv     = (const float*)d_in[6];
    const float* Wo     = (const float*)d_in[7];
    const float* bo     = (const float*)d_in[8];
    const float* logsig = (const float*)d_in[9];

    // ws layout (f16 units unless noted)
    f16*   xh    = (f16*)d_ws;              // 4,194,304
    f16*   wqkvh = xh + 4194304;            // 786,432
    f16*   woh   = wqkvh + 786432;          // 262,144
    f16*   qh    = woh + 262144;            // 4,194,304  [B,H,T,64]
    f16*   kh    = qh + 4194304;            // 4,194,304  [B,H,T,64]
    f16*   vtg   = kh + 4194304;            // 4,194,304  [B,H,64,T]
    float* ksqg  = (float*)(vtg + 4194304); // 65,536 f32
    f16*   abh   = xh;                      // alias: x dead after QKV GEMM

    convert_all<<<5120, 256, 0, stream>>>(x, Wq, Wk, Wv, Wo, xh, wqkvh, woh);

    gemm_mfma<1><<<dim3(64, 12), 256, 0, stream>>>(
        xh, wqkvh, bq, bk, bv, nullptr, qh, kh, vtg);

    ksq_kernel<<<1024, 256, 0, stream>>>(kh, ksqg);

    attn_v3<<<dim3(T_SEQ / 64, BATCH * NHEADS), 256, 0, stream>>>(
        qh, kh, vtg, ksqg, logsig, abh);

    gemm_mfma<0><<<dim3(64, 4), 256, 0, stream>>>(
        abh, woh, bo, nullptr, nullptr, (float*)d_out, nullptr, nullptr, nullptr);
}

// Round 4
// 177.408 us; speedup vs baseline: 4.3104x; 1.0822x over previous
//
#include <hip/hip_runtime.h>
#include <math.h>

#define T_SEQ   2048
#define EDIM    512
#define NHEADS  8
#define DHEAD   64
#define BATCH   4
#define WIN     128
#define TOPK    96

typedef _Float16 f16;
typedef f16 f16x2 __attribute__((ext_vector_type(2)));
typedef f16 f16x4 __attribute__((ext_vector_type(4)));
typedef f16 f16x8 __attribute__((ext_vector_type(8)));
typedef float f32x4 __attribute__((ext_vector_type(4)));

#define GLD_LDS(gp, lp) \
    __builtin_amdgcn_global_load_lds((const __attribute__((address_space(1))) void*)(gp), \
                                     (__attribute__((address_space(3))) void*)(lp), 16, 0, 0)

// ---------------------------------------------------------------------------
// fp32 -> f16 conversion of x, Wq, Wk, Wv, Wo. 4 elems/thread.
// ---------------------------------------------------------------------------
__global__ __launch_bounds__(256) void convert_all(
    const float* __restrict__ x,  const float* __restrict__ wq,
    const float* __restrict__ wk, const float* __restrict__ wv,
    const float* __restrict__ wo,
    f16* __restrict__ xh, f16* __restrict__ wqkvh, f16* __restrict__ woh)
{
    long i = ((long)blockIdx.x * 256 + threadIdx.x) * 4;
    const float* src; f16* dst; long off;
    if      (i < 4194304L) { src = x;  dst = xh;             off = i;            }
    else if (i < 4456448L) { src = wq; dst = wqkvh;          off = i - 4194304L; }
    else if (i < 4718592L) { src = wk; dst = wqkvh + 262144; off = i - 4456448L; }
    else if (i < 4980736L) { src = wv; dst = wqkvh + 524288; off = i - 4718592L; }
    else                   { src = wo; dst = woh;            off = i - 4980736L; }
    float4 v = *(const float4*)(src + off);
    f16x4 h; h.x = (f16)v.x; h.y = (f16)v.y; h.z = (f16)v.z; h.w = (f16)v.w;
    *(f16x4*)(dst + off) = h;
}

// ---------------------------------------------------------------------------
// QKV f16 MFMA GEMM (m97-pattern): 128x128 tile, BK=64, 256 threads.
// A=xh [8192x512], W=wqkvh [1536x512]. matrix = n0>>9:
//   Q,K -> f16 [B,H,T,64]; V -> f16 [B,H,64,T] (pre-transposed for PV).
// ---------------------------------------------------------------------------
__global__ __launch_bounds__(256) void gemm_qkv(
    const f16* __restrict__ A, const f16* __restrict__ W,
    const float* __restrict__ b0, const float* __restrict__ b1,
    const float* __restrict__ b2,
    f16* __restrict__ cq, f16* __restrict__ ck, f16* __restrict__ cv)
{
    __shared__ f16 Ash[16 * 512];
    __shared__ f16 Bsh[16 * 512];

    const int tid  = threadIdx.x;
    const int w    = tid >> 6;
    const int lane = tid & 63;
    const int m0   = blockIdx.x * 128;
    const int n0   = blockIdx.y * 128;
    const int K    = 512;
    const int lr   = lane & 15;
    const int lk8  = (lane >> 4) * 8;

    f32x4 acc[4][4];
#pragma unroll
    for (int i = 0; i < 4; i++)
#pragma unroll
        for (int j = 0; j < 4; j++) acc[i][j] = (f32x4){0.f, 0.f, 0.f, 0.f};

    const int wmi = (w & 1) * 4;
    const int wni = (w >> 1) * 4;

    for (int k0 = 0; k0 < K; k0 += 64) {
#pragma unroll
        for (int cc = 0; cc < 4; cc++) {
            const int c  = w * 4 + cc;
            const int ms = c & 7, kp = c >> 3;
            const int kcol = k0 + kp * 32 + lk8;
            GLD_LDS(A + (size_t)(m0 + ms * 16 + lr) * K + kcol, Ash + c * 512);
            GLD_LDS(W + (size_t)(n0 + ms * 16 + lr) * K + kcol, Bsh + c * 512);
        }
        __syncthreads();

#pragma unroll
        for (int kp = 0; kp < 2; kp++) {
            f16x8 af[4], bf[4];
#pragma unroll
            for (int i = 0; i < 4; i++)
                af[i] = *(const f16x8*)(Ash + (kp * 8 + wmi + i) * 512 + lane * 8);
#pragma unroll
            for (int j = 0; j < 4; j++)
                bf[j] = *(const f16x8*)(Bsh + (kp * 8 + wni + j) * 512 + lane * 8);
#pragma unroll
            for (int i = 0; i < 4; i++)
#pragma unroll
                for (int j = 0; j < 4; j++)
                    acc[i][j] = __builtin_amdgcn_mfma_f32_16x16x32_f16(af[i], bf[j], acc[i][j], 0, 0, 0);
        }
        __syncthreads();
    }

    const int quad = lane >> 4;
    const int mat = n0 >> 9;
    const float* bias = (mat == 0) ? b0 : ((mat == 1) ? b1 : b2);
#pragma unroll
    for (int i = 0; i < 4; i++) {
#pragma unroll
        for (int j = 0; j < 4; j++) {
            const int n    = n0 + (w >> 1) * 64 + j * 16 + lr;
            const int ncol = n & 511;
            const int h    = ncol >> 6, d = ncol & 63;
            const float bv = bias[ncol];
            if (mat < 2) {
                f16* dst = (mat == 0) ? cq : ck;
#pragma unroll
                for (int r = 0; r < 4; r++) {
                    const int m = m0 + (w & 1) * 64 + i * 16 + quad * 4 + r;
                    const int b = m >> 11, t = m & (T_SEQ - 1);
                    dst[((size_t)((b * NHEADS + h) * T_SEQ) + t) * 64 + d] =
                        (f16)(acc[i][j][r] + bv);
                }
            } else {
                const int mb = m0 + (w & 1) * 64 + i * 16 + quad * 4;
                const int b = mb >> 11, t = mb & (T_SEQ - 1);
                f16x4 pk;
#pragma unroll
                for (int r = 0; r < 4; r++) pk[r] = (f16)(acc[i][j][r] + bv);
                *(f16x4*)(cv + ((size_t)((b * NHEADS + h) * 64 + d)) * T_SEQ + t) = pk;
            }
        }
    }
}

// ---------------------------------------------------------------------------
// Output-projection GEMM: 128x64 tile, BK=64, 256 threads -> grid 64x8 = 512
// blocks (2/CU; the 128x128 version gave only 256 blocks = 1/CU, no overlap).
// ---------------------------------------------------------------------------
__global__ __launch_bounds__(256) void gemm_o(
    const f16* __restrict__ A, const f16* __restrict__ W,
    const float* __restrict__ bias, float* __restrict__ C)
{
    __shared__ f16 Ash[16 * 512];
    __shared__ f16 Bsh[8 * 512];

    const int tid  = threadIdx.x;
    const int w    = tid >> 6;
    const int lane = tid & 63;
    const int m0   = blockIdx.x * 128;
    const int n0   = blockIdx.y * 64;
    const int lr   = lane & 15;
    const int lk8  = (lane >> 4) * 8;

    f32x4 acc[4][2];
#pragma unroll
    for (int i = 0; i < 4; i++)
#pragma unroll
        for (int j = 0; j < 2; j++) acc[i][j] = (f32x4){0.f, 0.f, 0.f, 0.f};

    for (int k0 = 0; k0 < 512; k0 += 64) {
#pragma unroll
        for (int cc = 0; cc < 4; cc++) {          // A: 16 chunks
            const int c  = w * 4 + cc;
            const int ms = c & 7, kp = c >> 3;
            GLD_LDS(A + (size_t)(m0 + ms * 16 + lr) * 512 + k0 + kp * 32 + lk8, Ash + c * 512);
        }
#pragma unroll
        for (int cc = 0; cc < 2; cc++) {          // B: 8 chunks
            const int c  = w * 2 + cc;
            const int ns = c & 3, kp = c >> 2;
            GLD_LDS(W + (size_t)(n0 + ns * 16 + lr) * 512 + k0 + kp * 32 + lk8, Bsh + c * 512);
        }
        __syncthreads();

#pragma unroll
        for (int kp = 0; kp < 2; kp++) {
            f16x8 af[4], bf[2];
#pragma unroll
            for (int i = 0; i < 4; i++)
                af[i] = *(const f16x8*)(Ash + (kp * 8 + (w & 1) * 4 + i) * 512 + lane * 8);
#pragma unroll
            for (int j = 0; j < 2; j++)
                bf[j] = *(const f16x8*)(Bsh + (kp * 4 + (w >> 1) * 2 + j) * 512 + lane * 8);
#pragma unroll
            for (int i = 0; i < 4; i++)
#pragma unroll
                for (int j = 0; j < 2; j++)
                    acc[i][j] = __builtin_amdgcn_mfma_f32_16x16x32_f16(af[i], bf[j], acc[i][j], 0, 0, 0);
        }
        __syncthreads();
    }

    const int quad = lane >> 4;
#pragma unroll
    for (int i = 0; i < 4; i++) {
#pragma unroll
        for (int j = 0; j < 2; j++) {
            const int n  = n0 + (w >> 1) * 32 + j * 16 + lr;
            const float bv = bias[n];
#pragma unroll
            for (int r = 0; r < 4; r++) {
                const int m = m0 + (w & 1) * 64 + i * 16 + quad * 4 + r;
                C[(size_t)m * 512 + n] = acc[i][j][r] + bv;
            }
        }
    }
}

// ---------------------------------------------------------------------------
// Attention v4: block = 512 threads (8 waves), (b,h) x 64 queries.
// LDS (79.6 KB -> 2 blocks/CU = 4 waves/SIMD, double v3's occupancy):
//   region A @0:      Qs[64][88] f16 (11264) + Ks[192][88] f16 (33792)
//                     -> phase>=3: P[64][216] f16 (27648)
//   region B @45056:  Sc[64][132] f32 (33792) -> phase>=4: Vt[64][216] f16
//   ksqs @78848: f32[192]  (fused |k|^2: shuffle-reduced during K staging)
// Strides 88/216 f16 = 44/108 dwords -> 2-way bank aliasing (free) vs v3's
// 8-way at stride 200.
// Phase 3: 4 queries' ballot binary searches interleaved (4 indep chains).
// ---------------------------------------------------------------------------
__global__ __launch_bounds__(512, 4) void attn_v4(
    const f16* __restrict__ qh, const f16* __restrict__ kh,
    const f16* __restrict__ vtg, const float* __restrict__ logsig,
    f16* __restrict__ abh)
{
    __shared__ __align__(16) char smem[79616];
    f16*   Qs   = (f16*)smem;                 // [64][88]
    f16*   Ks   = (f16*)(smem + 11264);       // [192][88]
    f16*   P    = (f16*)smem;                 // [64][216] alias Qs/Ks
    float* Sc   = (float*)(smem + 45056);     // [64][132]
    f16*   Vt   = (f16*)(smem + 45056);       // [64][216] alias Sc
    float* ksqs = (float*)(smem + 78848);     // [192]

    const int tid = threadIdx.x, w = tid >> 6, lane = tid & 63;
    const int lr = lane & 15, quad = lane >> 4;
    const int q0 = blockIdx.x * 64, bh = blockIdx.y;
    const int h = bh & 7, b = bh >> 3;
    const size_t tb = (size_t)bh * T_SEQ;
    const int ks0 = q0 - 128;

    // ---- phase 1: stage Q, K (+fused |k|^2) ----
    {   // Qs: 512 chunks of 8 f16, exactly 1/thread
        const int row = tid >> 3, ch = tid & 7;
        f16x8 v = *(const f16x8*)(qh + (tb + q0 + row) * 64 + ch * 8);
        *(f16x8*)(Qs + row * 88 + ch * 8) = v;
    }
#pragma unroll
    for (int s = 0; s < 3; s++) {            // Ks: 1536 chunks, 3/thread
        const int i = tid + 512 * s;
        const int row = i >> 3, ch = i & 7;
        const int kg = ks0 + row;
        f16x8 v = {};
        if (kg >= 0) v = *(const f16x8*)(kh + (tb + kg) * 64 + ch * 8);
        *(f16x8*)(Ks + row * 88 + ch * 8) = v;
        float ps = 0.f;
#pragma unroll
        for (int j = 0; j < 8; j++) { const float fv = (float)v[j]; ps += fv * fv; }
        ps += __shfl_xor(ps, 1);
        ps += __shfl_xor(ps, 2);
        ps += __shfl_xor(ps, 4);             // 8 consecutive lanes = one row
        if (ch == 0) ksqs[row] = ps;
    }
    __syncthreads();

    // ---- phase 2: QK^T. wave = m-tile (w&3) x key-half (w>>2, 96 keys) ----
    const int mt  = w & 3;
    const int kh2 = w >> 2;
    f32x4 accQ[6];
#pragma unroll
    for (int jt = 0; jt < 6; jt++) accQ[jt] = (f32x4){0.f, 0.f, 0.f, 0.f};

#pragma unroll
    for (int kp = 0; kp < 2; kp++) {
        const f16x8 af = *(const f16x8*)(Qs + (mt * 16 + lr) * 88 + kp * 32 + quad * 8);
#pragma unroll
        for (int jt = 0; jt < 6; jt++) {
            const f16x8 bf = *(const f16x8*)(Ks + (kh2 * 96 + jt * 16 + lr) * 88 + kp * 32 + quad * 8);
            accQ[jt] = __builtin_amdgcn_mfma_f32_16x16x32_f16(af, bf, accQ[jt], 0, 0, 0);
        }
    }
    const float inv_s2 = __expf(-2.0f * logsig[h]);
#pragma unroll
    for (int jt = 0; jt < 6; jt++) {
        const int c  = kh2 * 96 + jt * 16 + lr;
        const float kq = ksqs[c];
        const int kg = ks0 + c;
#pragma unroll
        for (int r = 0; r < 4; r++) {
            const int dq = mt * 16 + quad * 4 + r;
            const unsigned wc = (unsigned)(c - dq - 1);
            if (wc < 128u) {
                Sc[dq * 132 + wc] = (kg >= 0) ? (accQ[jt][r] - 0.5f * kq) * inv_s2
                                              : -INFINITY;
            }
        }
    }
    __syncthreads();

    // ---- phase 3: exact top-96 via ballot binary search, 4 queries ILP ----
    const int wq8 = w * 8;
#pragma unroll 1
    for (int g = 0; g < 2; g++) {
        const int dq0 = wq8 + g * 4;
        float s0[4], s1[4], m[4];
        unsigned u0[4], u1[4], t[4];
#pragma unroll
        for (int qq = 0; qq < 4; qq++) {
            const int dq = dq0 + qq;
            s0[qq] = Sc[dq * 132 + lane];
            s1[qq] = Sc[dq * 132 + 64 + lane];
            const unsigned b0 = __float_as_uint(s0[qq]);
            const unsigned b1 = __float_as_uint(s1[qq]);
            u0[qq] = b0 ^ (unsigned)(((int)b0 >> 31) | 0x80000000);
            u1[qq] = b1 ^ (unsigned)(((int)b1 >> 31) | 0x80000000);
            // exp-shift: diagonal score (wc=127). Not necessarily the max,
            // but softmax is shift-exact; |s - s_diag| is small (window).
            m[qq] = __uint_as_float(__builtin_amdgcn_readlane(__float_as_uint(s1[qq]), 63));
            t[qq] = 0u;
        }
#pragma unroll
        for (int bit = 31; bit >= 0; bit--) {
#pragma unroll
            for (int qq = 0; qq < 4; qq++) {
                const unsigned c = t[qq] | (1u << bit);
                const int n = __popcll(__ballot(u0[qq] >= c)) +
                              __popcll(__ballot(u1[qq] >= c));
                if (n >= TOPK) t[qq] = c;
            }
        }
#pragma unroll
        for (int qq = 0; qq < 4; qq++) {
            const int dq = dq0 + qq;
            const float p0 = (u0[qq] >= t[qq]) ? __expf(s0[qq] - m[qq]) : 0.f;
            const float p1 = (u1[qq] >= t[qq]) ? __expf(s1[qq] - m[qq]) : 0.f;
            P[dq * 216 + dq + 1 + lane]  = (f16)p0;
            P[dq * 216 + dq + 65 + lane] = (f16)p1;
            P[dq * 216 + ((lane <= dq) ? lane : lane + 128)] = (f16)0.f;
        }
    }
    __syncthreads();

    // ---- phase 4: stage V^T (aliases Sc) ----
#pragma unroll
    for (int s = 0; s < 3; s++) {
        const int i = tid + 512 * s;          // 0..1535
        const int d = i / 24, ch = i % 24;
        const int t0 = ks0 + ch * 8;
        f16x8 vv = {};
        if (t0 >= 0) vv = *(const f16x8*)(vtg + ((size_t)bh * 64 + d) * T_SEQ + t0);
        *(f16x8*)(Vt + d * 216 + ch * 8) = vv;
    }
    __syncthreads();

    // ---- phase 5: PV MFMA. wave = m-tile (w&3) x d-half (w>>2, 32 dims) ----
    const int nh = w >> 2;
    f32x4 accO[2];
#pragma unroll
    for (int nt = 0; nt < 2; nt++) accO[nt] = (f32x4){0.f, 0.f, 0.f, 0.f};
    f32x4 accS = (f32x4){0.f, 0.f, 0.f, 0.f};
    f16x8 onesf;
#pragma unroll
    for (int j = 0; j < 8; j++) onesf[j] = (f16)1.0f;

#pragma unroll
    for (int ks = 0; ks < 6; ks++) {
        const f16x8 pf = *(const f16x8*)(P + (mt * 16 + lr) * 216 + ks * 32 + quad * 8);
#pragma unroll
        for (int nt = 0; nt < 2; nt++) {
            const f16x8 vf = *(const f16x8*)(Vt + (nh * 32 + nt * 16 + lr) * 216 + ks * 32 + quad * 8);
            accO[nt] = __builtin_amdgcn_mfma_f32_16x16x32_f16(pf, vf, accO[nt], 0, 0, 0);
        }
        accS = __builtin_amdgcn_mfma_f32_16x16x32_f16(pf, onesf, accS, 0, 0, 0);
    }
    float inv[4];
#pragma unroll
    for (int r = 0; r < 4; r++) inv[r] = 1.0f / accS[r];

#pragma unroll
    for (int nt = 0; nt < 2; nt++) {
        const int d = nh * 32 + nt * 16 + lr;
#pragma unroll
        for (int r = 0; r < 4; r++) {
            const int q = q0 + mt * 16 + quad * 4 + r;
            abh[((size_t)(b * T_SEQ + q)) * 512 + h * 64 + d] = (f16)(accO[nt][r] * inv[r]);
        }
    }
}

// ---------------------------------------------------------------------------
extern "C" void kernel_launch(void* const* d_in, const int* in_sizes, int n_in,
                              void* d_out, int out_size, void* d_ws, size_t ws_size,
                              hipStream_t stream)
{
    const float* x      = (const float*)d_in[0];
    const float* Wq     = (const float*)d_in[1];
    const float* bq     = (const float*)d_in[2];
    const float* Wk     = (const float*)d_in[3];
    const float* bk     = (const float*)d_in[4];
    const float* Wv     = (const float*)d_in[5];
    const float* bv     = (const float*)d_in[6];
    const float* Wo     = (const float*)d_in[7];
    const float* bo     = (const float*)d_in[8];
    const float* logsig = (const float*)d_in[9];

    f16* xh    = (f16*)d_ws;              // 4,194,304
    f16* wqkvh = xh + 4194304;            // 786,432
    f16* woh   = wqkvh + 786432;          // 262,144
    f16* qh    = woh + 262144;            // 4,194,304  [B,H,T,64]
    f16* kh    = qh + 4194304;            // 4,194,304  [B,H,T,64]
    f16* vtg   = kh + 4194304;            // 4,194,304  [B,H,64,T]
    f16* abh   = xh;                      // alias: x dead after QKV GEMM

    convert_all<<<5120, 256, 0, stream>>>(x, Wq, Wk, Wv, Wo, xh, wqkvh, woh);

    gemm_qkv<<<dim3(64, 12), 256, 0, stream>>>(xh, wqkvh, bq, bk, bv, qh, kh, vtg);

    attn_v4<<<dim3(T_SEQ / 64, BATCH * NHEADS), 512, 0, stream>>>(
        qh, kh, vtg, logsig, abh);

    gemm_o<<<dim3(64, 8), 256, 0, stream>>>(abh, woh, bo, (float*)d_out);
}

// Round 5
// 172.933 us; speedup vs baseline: 4.4219x; 1.0259x over previous
//
#include <hip/hip_runtime.h>
#include <math.h>

#define T_SEQ   2048
#define EDIM    512
#define NHEADS  8
#define DHEAD   64
#define BATCH   4
#define WIN     128
#define TOPK    96

typedef _Float16 f16;
typedef f16 f16x2 __attribute__((ext_vector_type(2)));
typedef f16 f16x4 __attribute__((ext_vector_type(4)));
typedef f16 f16x8 __attribute__((ext_vector_type(8)));
typedef float f32x4 __attribute__((ext_vector_type(4)));

#define GLD_LDS(gp, lp) \
    __builtin_amdgcn_global_load_lds((const __attribute__((address_space(1))) void*)(gp), \
                                     (__attribute__((address_space(3))) void*)(lp), 16, 0, 0)

// ---------------------------------------------------------------------------
// fp32 -> f16 conversion of x, Wq, Wk, Wv, Wo. 4 elems/thread.
// ---------------------------------------------------------------------------
__global__ __launch_bounds__(256) void convert_all(
    const float* __restrict__ x,  const float* __restrict__ wq,
    const float* __restrict__ wk, const float* __restrict__ wv,
    const float* __restrict__ wo,
    f16* __restrict__ xh, f16* __restrict__ wqkvh, f16* __restrict__ woh)
{
    long i = ((long)blockIdx.x * 256 + threadIdx.x) * 4;
    const float* src; f16* dst; long off;
    if      (i < 4194304L) { src = x;  dst = xh;             off = i;            }
    else if (i < 4456448L) { src = wq; dst = wqkvh;          off = i - 4194304L; }
    else if (i < 4718592L) { src = wk; dst = wqkvh + 262144; off = i - 4456448L; }
    else if (i < 4980736L) { src = wv; dst = wqkvh + 524288; off = i - 4718592L; }
    else                   { src = wo; dst = woh;            off = i - 4980736L; }
    float4 v = *(const float4*)(src + off);
    f16x4 h; h.x = (f16)v.x; h.y = (f16)v.y; h.z = (f16)v.z; h.w = (f16)v.w;
    *(f16x4*)(dst + off) = h;
}

// ---------------------------------------------------------------------------
// QKV f16 MFMA GEMM (m97-pattern): 128x128 tile, BK=64, 256 threads.
// A=xh [8192x512], W=wqkvh [1536x512]. matrix = n0>>9:
//   Q,K -> f16 [B,H,T,64]; V -> f16 [B,H,64,T] (pre-transposed for PV).
// Epilogue v5: LDS-transpose (reusing the 32KB staging buffer) so all global
// stores are 16B coalesced f16x8 (was: 48x b16 + 16x scattered b64 per thread).
//   Q/K: [m][n] tile, XOR-swizzle n^=((m>>2)&7)<<4  (column writes -> 4
//        disjoint 8-dword bank groups; row reads stay 16B-aligned/contig).
//   V:   [n][m] tile, rotation m'=(m+8*(n&15))&127 (f16x4 column writes spread
//        across banks; row reads permuted but conflict-free).
// ---------------------------------------------------------------------------
__global__ __launch_bounds__(256) void gemm_qkv(
    const f16* __restrict__ A, const f16* __restrict__ W,
    const float* __restrict__ b0, const float* __restrict__ b1,
    const float* __restrict__ b2,
    f16* __restrict__ cq, f16* __restrict__ ck, f16* __restrict__ cv)
{
    __shared__ f16 SH[16384];           // staging: Ash=SH[0:8192), Bsh=[8192:16384); epilogue: 128x128 tile
    f16* Ash = SH;
    f16* Bsh = SH + 8192;

    const int tid  = threadIdx.x;
    const int w    = tid >> 6;
    const int lane = tid & 63;
    const int m0   = blockIdx.x * 128;
    const int n0   = blockIdx.y * 128;
    const int K    = 512;
    const int lr   = lane & 15;
    const int lk8  = (lane >> 4) * 8;

    f32x4 acc[4][4];
#pragma unroll
    for (int i = 0; i < 4; i++)
#pragma unroll
        for (int j = 0; j < 4; j++) acc[i][j] = (f32x4){0.f, 0.f, 0.f, 0.f};

    const int wmi = (w & 1) * 4;
    const int wni = (w >> 1) * 4;

    for (int k0 = 0; k0 < K; k0 += 64) {
#pragma unroll
        for (int cc = 0; cc < 4; cc++) {
            const int c  = w * 4 + cc;
            const int ms = c & 7, kp = c >> 3;
            const int kcol = k0 + kp * 32 + lk8;
            GLD_LDS(A + (size_t)(m0 + ms * 16 + lr) * K + kcol, Ash + c * 512);
            GLD_LDS(W + (size_t)(n0 + ms * 16 + lr) * K + kcol, Bsh + c * 512);
        }
        __syncthreads();

#pragma unroll
        for (int kp = 0; kp < 2; kp++) {
            f16x8 af[4], bf[4];
#pragma unroll
            for (int i = 0; i < 4; i++)
                af[i] = *(const f16x8*)(Ash + (kp * 8 + wmi + i) * 512 + lane * 8);
#pragma unroll
            for (int j = 0; j < 4; j++)
                bf[j] = *(const f16x8*)(Bsh + (kp * 8 + wni + j) * 512 + lane * 8);
#pragma unroll
            for (int i = 0; i < 4; i++)
#pragma unroll
                for (int j = 0; j < 4; j++)
                    acc[i][j] = __builtin_amdgcn_mfma_f32_16x16x32_f16(af[i], bf[j], acc[i][j], 0, 0, 0);
        }
        __syncthreads();   // also guards SH reuse by the epilogue
    }

    const int quad = lane >> 4;
    const int mat  = n0 >> 9;
    const float* bias = (mat == 0) ? b0 : ((mat == 1) ? b1 : b2);
    const int bb  = m0 >> 11;            // batch (m0 multiple of 128, T=2048)
    const int t0  = m0 & (T_SEQ - 1);
    const int hh0 = (n0 & 511) >> 6;     // first head covered by this n-tile

    if (mat < 2) {
        // ---- Q/K: swizzled [m][n] tile ----
#pragma unroll
        for (int i = 0; i < 4; i++) {
#pragma unroll
            for (int j = 0; j < 4; j++) {
                const int nl = (w >> 1) * 64 + j * 16 + lr;
                const float bvv = bias[(n0 & 511) + nl];
#pragma unroll
                for (int r = 0; r < 4; r++) {
                    const int ml = (w & 1) * 64 + i * 16 + quad * 4 + r;
                    SH[ml * 128 + (nl ^ (((ml >> 2) & 7) << 4))] = (f16)(acc[i][j][r] + bvv);
                }
            }
        }
        __syncthreads();
        f16* dst = (mat == 0) ? cq : ck;
#pragma unroll
        for (int s = 0; s < 8; s++) {
            const int c   = tid + 256 * s;        // 0..2047 chunks of f16x8
            const int row = c >> 4;               // m-row 0..127
            const int nt  = (c & 15) * 8;         // true n base
            const f16x8 vv = *(const f16x8*)&SH[row * 128 + (nt ^ (((row >> 2) & 7) << 4))];
            const int hh = hh0 + (nt >> 6);
            const int dd = nt & 63;
            *(f16x8*)(dst + ((size_t)((bb * NHEADS + hh) * T_SEQ) + t0 + row) * 64 + dd) = vv;
        }
    } else {
        // ---- V: rotated [n][m] tile (transpose to [B,H,64,T]) ----
#pragma unroll
        for (int i = 0; i < 4; i++) {
#pragma unroll
            for (int j = 0; j < 4; j++) {
                const int nl = (w >> 1) * 64 + j * 16 + lr;
                const float bvv = bias[(n0 & 511) + nl];
                const int mlb = (w & 1) * 64 + i * 16 + quad * 4;
                f16x4 pk;
#pragma unroll
                for (int r = 0; r < 4; r++) pk[r] = (f16)(acc[i][j][r] + bvv);
                *(f16x4*)&SH[nl * 128 + ((mlb + 8 * (nl & 15)) & 127)] = pk;
            }
        }
        __syncthreads();
#pragma unroll
        for (int s = 0; s < 8; s++) {
            const int c    = tid + 256 * s;       // 0..2047
            const int nrow = c >> 4;              // d-row 0..127 (2 heads)
            const int cht  = c & 15;              // true m-chunk
            const int chl  = (cht + (nrow & 15)) & 15;
            const f16x8 vv = *(const f16x8*)&SH[nrow * 128 + chl * 8];
            const int hh = hh0 + (nrow >> 6);
            const int dd = nrow & 63;
            *(f16x8*)(cv + ((size_t)((bb * NHEADS + hh) * 64 + dd)) * T_SEQ + t0 + cht * 8) = vv;
        }
    }
}

// ---------------------------------------------------------------------------
// Output-projection GEMM: 128x64 tile, BK=64, 256 threads -> 512 blocks (2/CU).
// ---------------------------------------------------------------------------
__global__ __launch_bounds__(256) void gemm_o(
    const f16* __restrict__ A, const f16* __restrict__ W,
    const float* __restrict__ bias, float* __restrict__ C)
{
    __shared__ f16 Ash[16 * 512];
    __shared__ f16 Bsh[8 * 512];

    const int tid  = threadIdx.x;
    const int w    = tid >> 6;
    const int lane = tid & 63;
    const int m0   = blockIdx.x * 128;
    const int n0   = blockIdx.y * 64;
    const int lr   = lane & 15;
    const int lk8  = (lane >> 4) * 8;

    f32x4 acc[4][2];
#pragma unroll
    for (int i = 0; i < 4; i++)
#pragma unroll
        for (int j = 0; j < 2; j++) acc[i][j] = (f32x4){0.f, 0.f, 0.f, 0.f};

    for (int k0 = 0; k0 < 512; k0 += 64) {
#pragma unroll
        for (int cc = 0; cc < 4; cc++) {          // A: 16 chunks
            const int c  = w * 4 + cc;
            const int ms = c & 7, kp = c >> 3;
            GLD_LDS(A + (size_t)(m0 + ms * 16 + lr) * 512 + k0 + kp * 32 + lk8, Ash + c * 512);
        }
#pragma unroll
        for (int cc = 0; cc < 2; cc++) {          // B: 8 chunks
            const int c  = w * 2 + cc;
            const int ns = c & 3, kp = c >> 2;
            GLD_LDS(W + (size_t)(n0 + ns * 16 + lr) * 512 + k0 + kp * 32 + lk8, Bsh + c * 512);
        }
        __syncthreads();

#pragma unroll
        for (int kp = 0; kp < 2; kp++) {
            f16x8 af[4], bf[2];
#pragma unroll
            for (int i = 0; i < 4; i++)
                af[i] = *(const f16x8*)(Ash + (kp * 8 + (w & 1) * 4 + i) * 512 + lane * 8);
#pragma unroll
            for (int j = 0; j < 2; j++)
                bf[j] = *(const f16x8*)(Bsh + (kp * 4 + (w >> 1) * 2 + j) * 512 + lane * 8);
#pragma unroll
            for (int i = 0; i < 4; i++)
#pragma unroll
                for (int j = 0; j < 2; j++)
                    acc[i][j] = __builtin_amdgcn_mfma_f32_16x16x32_f16(af[i], bf[j], acc[i][j], 0, 0, 0);
        }
        __syncthreads();
    }

    const int quad = lane >> 4;
#pragma unroll
    for (int i = 0; i < 4; i++) {
#pragma unroll
        for (int j = 0; j < 2; j++) {
            const int n  = n0 + (w >> 1) * 32 + j * 16 + lr;
            const float bv = bias[n];
#pragma unroll
            for (int r = 0; r < 4; r++) {
                const int m = m0 + (w & 1) * 64 + i * 16 + quad * 4 + r;
                C[(size_t)m * 512 + n] = acc[i][j][r] + bv;
            }
        }
    }
}

// ---------------------------------------------------------------------------
// Attention v4 (unchanged from round 4): block = 512 threads (8 waves),
// (b,h) x 64 queries. LDS 79.6 KB -> 2 blocks/CU = 4 waves/SIMD.
// ---------------------------------------------------------------------------
__global__ __launch_bounds__(512, 4) void attn_v4(
    const f16* __restrict__ qh, const f16* __restrict__ kh,
    const f16* __restrict__ vtg, const float* __restrict__ logsig,
    f16* __restrict__ abh)
{
    __shared__ __align__(16) char smem[79616];
    f16*   Qs   = (f16*)smem;                 // [64][88]
    f16*   Ks   = (f16*)(smem + 11264);       // [192][88]
    f16*   P    = (f16*)smem;                 // [64][216] alias Qs/Ks
    float* Sc   = (float*)(smem + 45056);     // [64][132]
    f16*   Vt   = (f16*)(smem + 45056);       // [64][216] alias Sc
    float* ksqs = (float*)(smem + 78848);     // [192]

    const int tid = threadIdx.x, w = tid >> 6, lane = tid & 63;
    const int lr = lane & 15, quad = lane >> 4;
    const int q0 = blockIdx.x * 64, bh = blockIdx.y;
    const int h = bh & 7, b = bh >> 3;
    const size_t tb = (size_t)bh * T_SEQ;
    const int ks0 = q0 - 128;

    // ---- phase 1: stage Q, K (+fused |k|^2) ----
    {
        const int row = tid >> 3, ch = tid & 7;
        f16x8 v = *(const f16x8*)(qh + (tb + q0 + row) * 64 + ch * 8);
        *(f16x8*)(Qs + row * 88 + ch * 8) = v;
    }
#pragma unroll
    for (int s = 0; s < 3; s++) {
        const int i = tid + 512 * s;
        const int row = i >> 3, ch = i & 7;
        const int kg = ks0 + row;
        f16x8 v = {};
        if (kg >= 0) v = *(const f16x8*)(kh + (tb + kg) * 64 + ch * 8);
        *(f16x8*)(Ks + row * 88 + ch * 8) = v;
        float ps = 0.f;
#pragma unroll
        for (int j = 0; j < 8; j++) { const float fv = (float)v[j]; ps += fv * fv; }
        ps += __shfl_xor(ps, 1);
        ps += __shfl_xor(ps, 2);
        ps += __shfl_xor(ps, 4);
        if (ch == 0) ksqs[row] = ps;
    }
    __syncthreads();

    // ---- phase 2: QK^T. wave = m-tile (w&3) x key-half (w>>2, 96 keys) ----
    const int mt  = w & 3;
    const int kh2 = w >> 2;
    f32x4 accQ[6];
#pragma unroll
    for (int jt = 0; jt < 6; jt++) accQ[jt] = (f32x4){0.f, 0.f, 0.f, 0.f};

#pragma unroll
    for (int kp = 0; kp < 2; kp++) {
        const f16x8 af = *(const f16x8*)(Qs + (mt * 16 + lr) * 88 + kp * 32 + quad * 8);
#pragma unroll
        for (int jt = 0; jt < 6; jt++) {
            const f16x8 bf = *(const f16x8*)(Ks + (kh2 * 96 + jt * 16 + lr) * 88 + kp * 32 + quad * 8);
            accQ[jt] = __builtin_amdgcn_mfma_f32_16x16x32_f16(af, bf, accQ[jt], 0, 0, 0);
        }
    }
    const float inv_s2 = __expf(-2.0f * logsig[h]);
#pragma unroll
    for (int jt = 0; jt < 6; jt++) {
        const int c  = kh2 * 96 + jt * 16 + lr;
        const float kq = ksqs[c];
        const int kg = ks0 + c;
#pragma unroll
        for (int r = 0; r < 4; r++) {
            const int dq = mt * 16 + quad * 4 + r;
            const unsigned wc = (unsigned)(c - dq - 1);
            if (wc < 128u) {
                Sc[dq * 132 + wc] = (kg >= 0) ? (accQ[jt][r] - 0.5f * kq) * inv_s2
                                              : -INFINITY;
            }
        }
    }
    __syncthreads();

    // ---- phase 3: exact top-96 via ballot binary search, 4 queries ILP ----
    const int wq8 = w * 8;
#pragma unroll 1
    for (int g = 0; g < 2; g++) {
        const int dq0 = wq8 + g * 4;
        float s0[4], s1[4], m[4];
        unsigned u0[4], u1[4], t[4];
#pragma unroll
        for (int qq = 0; qq < 4; qq++) {
            const int dq = dq0 + qq;
            s0[qq] = Sc[dq * 132 + lane];
            s1[qq] = Sc[dq * 132 + 64 + lane];
            const unsigned b0 = __float_as_uint(s0[qq]);
            const unsigned b1 = __float_as_uint(s1[qq]);
            u0[qq] = b0 ^ (unsigned)(((int)b0 >> 31) | 0x80000000);
            u1[qq] = b1 ^ (unsigned)(((int)b1 >> 31) | 0x80000000);
            m[qq] = __uint_as_float(__builtin_amdgcn_readlane(__float_as_uint(s1[qq]), 63));
            t[qq] = 0u;
        }
#pragma unroll
        for (int bit = 31; bit >= 0; bit--) {
#pragma unroll
            for (int qq = 0; qq < 4; qq++) {
                const unsigned c = t[qq] | (1u << bit);
                const int n = __popcll(__ballot(u0[qq] >= c)) +
                              __popcll(__ballot(u1[qq] >= c));
                if (n >= TOPK) t[qq] = c;
            }
        }
#pragma unroll
        for (int qq = 0; qq < 4; qq++) {
            const int dq = dq0 + qq;
            const float p0 = (u0[qq] >= t[qq]) ? __expf(s0[qq] - m[qq]) : 0.f;
            const float p1 = (u1[qq] >= t[qq]) ? __expf(s1[qq] - m[qq]) : 0.f;
            P[dq * 216 + dq + 1 + lane]  = (f16)p0;
            P[dq * 216 + dq + 65 + lane] = (f16)p1;
            P[dq * 216 + ((lane <= dq) ? lane : lane + 128)] = (f16)0.f;
        }
    }
    __syncthreads();

    // ---- phase 4: stage V^T (aliases Sc) ----
#pragma unroll
    for (int s = 0; s < 3; s++) {
        const int i = tid + 512 * s;
        const int d = i / 24, ch = i % 24;
        const int t0 = ks0 + ch * 8;
        f16x8 vv = {};
        if (t0 >= 0) vv = *(const f16x8*)(vtg + ((size_t)bh * 64 + d) * T_SEQ + t0);
        *(f16x8*)(Vt + d * 216 + ch * 8) = vv;
    }
    __syncthreads();

    // ---- phase 5: PV MFMA + ones-MFMA row sums ----
    const int nh = w >> 2;
    f32x4 accO[2];
#pragma unroll
    for (int nt = 0; nt < 2; nt++) accO[nt] = (f32x4){0.f, 0.f, 0.f, 0.f};
    f32x4 accS = (f32x4){0.f, 0.f, 0.f, 0.f};
    f16x8 onesf;
#pragma unroll
    for (int j = 0; j < 8; j++) onesf[j] = (f16)1.0f;

#pragma unroll
    for (int ks = 0; ks < 6; ks++) {
        const f16x8 pf = *(const f16x8*)(P + (mt * 16 + lr) * 216 + ks * 32 + quad * 8);
#pragma unroll
        for (int nt = 0; nt < 2; nt++) {
            const f16x8 vf = *(const f16x8*)(Vt + (nh * 32 + nt * 16 + lr) * 216 + ks * 32 + quad * 8);
            accO[nt] = __builtin_amdgcn_mfma_f32_16x16x32_f16(pf, vf, accO[nt], 0, 0, 0);
        }
        accS = __builtin_amdgcn_mfma_f32_16x16x32_f16(pf, onesf, accS, 0, 0, 0);
    }
    float inv[4];
#pragma unroll
    for (int r = 0; r < 4; r++) inv[r] = 1.0f / accS[r];

#pragma unroll
    for (int nt = 0; nt < 2; nt++) {
        const int d = nh * 32 + nt * 16 + lr;
#pragma unroll
        for (int r = 0; r < 4; r++) {
            const int q = q0 + mt * 16 + quad * 4 + r;
            abh[((size_t)(b * T_SEQ + q)) * 512 + h * 64 + d] = (f16)(accO[nt][r] * inv[r]);
        }
    }
}

// ---------------------------------------------------------------------------
extern "C" void kernel_launch(void* const* d_in, const int* in_sizes, int n_in,
                              void* d_out, int out_size, void* d_ws, size_t ws_size,
                              hipStream_t stream)
{
    const float* x      = (const float*)d_in[0];
    const float* Wq     = (const float*)d_in[1];
    const float* bq     = (const float*)d_in[2];
    const float* Wk     = (const float*)d_in[3];
    const float* bk     = (const float*)d_in[4];
    const float* Wv     = (const float*)d_in[5];
    const float* bv     = (const float*)d_in[6];
    const float* Wo     = (const float*)d_in[7];
    const float* bo     = (const float*)d_in[8];
    const float* logsig = (const float*)d_in[9];

    f16* xh    = (f16*)d_ws;              // 4,194,304
    f16* wqkvh = xh + 4194304;            // 786,432
    f16* woh   = wqkvh + 786432;          // 262,144
    f16* qh    = woh + 262144;            // 4,194,304  [B,H,T,64]
    f16* kh    = qh + 4194304;            // 4,194,304  [B,H,T,64]
    f16* vtg   = kh + 4194304;            // 4,194,304  [B,H,64,T]
    f16* abh   = xh;                      // alias: x dead after QKV GEMM

    convert_all<<<5120, 256, 0, stream>>>(x, Wq, Wk, Wv, Wo, xh, wqkvh, woh);

    gemm_qkv<<<dim3(64, 12), 256, 0, stream>>>(xh, wqkvh, bq, bk, bv, qh, kh, vtg);

    attn_v4<<<dim3(T_SEQ / 64, BATCH * NHEADS), 512, 0, stream>>>(
        qh, kh, vtg, logsig, abh);

    gemm_o<<<dim3(64, 8), 256, 0, stream>>>(abh, woh, bo, (float*)d_out);
}